// Round 4
// baseline (155.303 us; speedup 1.0000x reference)
//
#include <hip/hip_runtime.h>
#include <math.h>

// Problem dims (fixed per reference)
#define B_DIM 32
#define C_DIM 256
#define K_DIM 32
#define N_DIM 4096   // 64*64
#define TC    32     // channels per LDS tile
#define NSLICE 16    // N_DIM / 256

// ws layout (float offsets) — every slot fully overwritten each call,
// no zeroing needed, no atomics anywhere.
//   [0,      8192)   cw_t  [C][K]        (transposed codewords)
//   [8192,   8224)   c2    [K]
//   [8224, 139296)   Spart [B][16][C]    (per-slice partial row sums)
//   [139296,155680)  a_part[B][16][K]    (per-slice partial a sums)
#define WS_CWT   0
#define WS_C2    8192
#define WS_SPART 8224
#define WS_APART 139296

__global__ void ce_prep_kernel(const float* __restrict__ cw, float* __restrict__ ws) {
    float* cw_t = ws + WS_CWT;
    float* c2   = ws + WS_C2;
    int c = threadIdx.x;  // 256 threads
    #pragma unroll
    for (int k = 0; k < K_DIM; ++k)
        cw_t[c * K_DIM + k] = cw[k * C_DIM + c];
    if (c < K_DIM) {
        int k = c;
        float s = 0.f;
        for (int cc = 0; cc < C_DIM; ++cc) {
            float v = cw[k * C_DIM + cc];
            s = fmaf(v, v, s);
        }
        c2[k] = s;
    }
}

// Stage one wave-private [TC c][64 px] fp32 tile. Each of the 8 instrs
// covers 4 c-rows: lane l -> row (l>>4), px (l&15)*4, 16 B. LDS dst is
// wave-uniform base + lane*16 (linear), matching exactly.
__device__ __forceinline__ void stage_tile(const float* __restrict__ xw,
                                           float* ldsbase, int c0, int lane) {
    #pragma unroll
    for (int i = 0; i < 8; ++i) {
        const float* src = xw + (size_t)(c0 + i * 4 + (lane >> 4)) * N_DIM
                              + ((lane & 15) << 2);
        __builtin_amdgcn_global_load_lds(
            (const __attribute__((address_space(1))) void*)src,
            (__attribute__((address_space(3))) void*)(ldsbase + i * 256),
            16, 0, 0);
    }
}

__global__ __launch_bounds__(256, 2)
void ce_main_kernel(const float* __restrict__ x,
                    const float* __restrict__ scale,
                    const float* __restrict__ cw_t,
                    const float* __restrict__ c2,
                    float* __restrict__ Spart,
                    float* __restrict__ a_part) {
    __shared__ float tile[2][4][TC * 64];   // 64 KB, wave-private quarters
    __shared__ float sA[4][C_DIM];          // 4 KB  (per-wave S partials)
    __shared__ float awave[4][K_DIM];       // 512 B (per-wave a partials)

    const int tid  = threadIdx.x;
    const int wave = tid >> 6;
    const int lane = tid & 63;
    const int s    = blockIdx.x;             // slice 0..15
    const int b    = blockIdx.y;             // 0..31

    // this wave's 64-pixel column base
    const float* xw = x + (size_t)b * ((size_t)C_DIM * N_DIM) + s * 256 + wave * 64;

    float dot[K_DIM];
    #pragma unroll
    for (int k = 0; k < K_DIM; ++k) dot[k] = 0.f;
    float f2 = 0.f;
    float S8[8];
    #pragma unroll
    for (int t = 0; t < 8; ++t) S8[t] = 0.f;

    float* tl0 = &tile[0][wave][0];
    float* tl1 = &tile[1][wave][0];

    stage_tile(xw, tl0, 0, lane);
    asm volatile("s_waitcnt vmcnt(0)" ::: "memory");

    for (int t = 0; t < 8; ++t) {
        float* curb = (t & 1) ? tl1 : tl0;
        float* nxtb = (t & 1) ? tl0 : tl1;
        if (t < 7) stage_tile(xw, nxtb, (t + 1) * TC, lane);

        const float* cwb = cw_t + t * TC * K_DIM;
        #pragma unroll 4
        for (int cc = 0; cc < TC; ++cc) {
            float f = curb[cc * 64 + lane];
            f2 = fmaf(f, f, f2);
            const float* cwc = cwb + cc * K_DIM;  // wave-uniform -> scalar loads
            #pragma unroll
            for (int k = 0; k < K_DIM; ++k)
                dot[k] = fmaf(f, cwc[k], dot[k]);
        }

        // S partial for this tile: lane sums half (lane>>5) of c-row (lane&31).
        // XOR-rotate the float4 order so the 8 lanes sharing (lane&7) spread
        // their issue across bank-quads; order of summation is irrelevant.
        {
            const float4* rowp =
                (const float4*)(curb + (lane & 31) * 64 + (lane >> 5) * 32);
            float acc = 0.f;
            #pragma unroll
            for (int j = 0; j < 8; ++j) {
                float4 v = rowp[j ^ (lane & 7)];
                acc += (v.x + v.y) + (v.z + v.w);
            }
            S8[t] = acc;
        }

        // wave-local drain: next iteration reads the prefetched buffer
        asm volatile("s_waitcnt vmcnt(0)" ::: "memory");
    }

    // per-thread softmax over k (numerically stable)
    float a[K_DIM];
    float m = -1e30f;
    #pragma unroll
    for (int k = 0; k < K_DIM; ++k) {
        float d2 = f2 + c2[k] - 2.f * dot[k];
        float dist = sqrtf(fmaxf(d2, 0.f));
        float L = -dist * scale[k];
        a[k] = L;
        m = fmaxf(m, L);
    }
    float sum = 0.f;
    #pragma unroll
    for (int k = 0; k < K_DIM; ++k) {
        float e = __expf(a[k] - m);
        a[k] = e;
        sum += e;
    }
    float inv = 1.f / sum;

    // wave-reduce each a[k]; lane k keeps the wave total (once per kernel)
    float mine = 0.f;
    #pragma unroll
    for (int k = 0; k < K_DIM; ++k) {
        float v = a[k] * inv;
        v += __shfl_xor(v, 1);
        v += __shfl_xor(v, 2);
        v += __shfl_xor(v, 4);
        v += __shfl_xor(v, 8);
        v += __shfl_xor(v, 16);
        v += __shfl_xor(v, 32);
        if (lane == k) mine = v;
    }
    if (lane < K_DIM) awave[wave][lane] = mine;

    // fold the two half-row S partials, park per-wave S in LDS
    #pragma unroll
    for (int t = 0; t < 8; ++t) S8[t] += __shfl_xor(S8[t], 32);
    if (lane < 32) {
        #pragma unroll
        for (int t = 0; t < 8; ++t) sA[wave][t * 32 + lane] = S8[t];
    }
    __syncthreads();

    // cross-wave combine (single barrier in the kernel)
    float Ssum = sA[0][tid] + sA[1][tid] + sA[2][tid] + sA[3][tid];
    Spart[((size_t)b * NSLICE + s) * C_DIM + tid] = Ssum;
    if (tid < K_DIM) {
        a_part[((size_t)b * NSLICE + s) * K_DIM + tid] =
            awave[0][tid] + awave[1][tid] + awave[2][tid] + awave[3][tid];
    }
}

__global__ void ce_final_kernel(float* __restrict__ out,
                                const float* __restrict__ cw_t,
                                const float* __restrict__ Spart,
                                const float* __restrict__ a_part) {
    __shared__ float asum_l[K_DIM];
    const int b = blockIdx.x;
    const int c = threadIdx.x;

    if (c < K_DIM) {
        float a = 0.f;
        #pragma unroll
        for (int s = 0; s < NSLICE; ++s)
            a += a_part[((size_t)b * NSLICE + s) * K_DIM + c];
        asum_l[c] = a;
    }
    __syncthreads();

    float S = 0.f;
    #pragma unroll
    for (int s = 0; s < NSLICE; ++s)
        S += Spart[((size_t)b * NSLICE + s) * C_DIM + c];

    float acc = 0.f;
    #pragma unroll
    for (int k = 0; k < K_DIM; ++k)
        acc = fmaf(asum_l[k], cw_t[c * K_DIM + k], acc);
    out[b * C_DIM + c] = (S - acc) * (1.0f / (float)K_DIM);
}

extern "C" void kernel_launch(void* const* d_in, const int* in_sizes, int n_in,
                              void* d_out, int out_size, void* d_ws, size_t ws_size,
                              hipStream_t stream) {
    const float* x     = (const float*)d_in[0];
    const float* cw    = (const float*)d_in[1];
    const float* scale = (const float*)d_in[2];
    float* out = (float*)d_out;
    float* ws  = (float*)d_ws;

    ce_prep_kernel<<<1, 256, 0, stream>>>(cw, ws);

    dim3 grid(NSLICE, B_DIM);
    ce_main_kernel<<<grid, 256, 0, stream>>>(x, scale,
                                             ws + WS_CWT, ws + WS_C2,
                                             ws + WS_SPART, ws + WS_APART);

    ce_final_kernel<<<B_DIM, 256, 0, stream>>>(out, ws + WS_CWT,
                                               ws + WS_SPART, ws + WS_APART);
}

// Round 5
// 45.003 us; speedup vs baseline: 3.4510x; 3.4510x over previous
//
#include <hip/hip_runtime.h>
#include <hip/hip_bf16.h>
#include <math.h>

// Problem dims (fixed per reference)
#define B_DIM 32
#define C_DIM 256
#define K_DIM 32
#define N_DIM 4096   // 64*64
#define NSLICE 16    // N/256 pixel slices
#define RS 66        // padded dword stride per c-pair row (16 rows/tile)

typedef short v8s __attribute__((ext_vector_type(8)));   // 8 bf16
typedef float v4f __attribute__((ext_vector_type(4)));   // MFMA acc

// ws float offsets — every slot overwritten each call, no zeroing, no atomics
//   [0,    32)      c2   [K]
//   [32,   4128)    cw_bf16 [K][C] as u16 (16 KB)
//   [4128, 135200)  Spart [B][16][C]
//   [135200,151584) a_part[B][16][K]
#define WS_C2    0
#define WS_CWB   32
#define WS_SPART 4128
#define WS_APART 135200

__global__ void ce_prep(const float* __restrict__ cw, float* __restrict__ ws) {
    const int j = threadIdx.x;  // 256 threads
    unsigned short* cwb = (unsigned short*)(ws + WS_CWB);
    #pragma unroll
    for (int r = 0; r < K_DIM; ++r) {
        int idx = r * C_DIM + j;
        union { __hip_bfloat16 h; unsigned short u; } cv;
        cv.h = __float2bfloat16(cw[idx]);
        cwb[idx] = cv.u;
    }
    if (j < K_DIM) {
        float s = 0.f;
        for (int cc = 0; cc < C_DIM; ++cc) {
            float v = cw[j * C_DIM + cc];
            s = fmaf(v, v, s);
        }
        ws[WS_C2 + j] = s;
    }
}

__global__ __launch_bounds__(256, 2)
void ce_main(const float* __restrict__ x,
             const float* __restrict__ scale,
             const float* __restrict__ ws_ro,
             float* __restrict__ Spart,
             float* __restrict__ a_part) {
    __shared__ float buf[2][4][16 * RS];   // 33 KB: per-wave double-buffered tiles
    __shared__ float sA[4][C_DIM];         // per-wave S partials
    __shared__ float awv[4][K_DIM];        // per-wave a partials
    __shared__ float f2s[4][64];           // per-wave f2 redistribution

    const int tid   = threadIdx.x;
    const int wave  = tid >> 6;
    const int lane  = tid & 63;
    const int g     = lane >> 4;   // 16-lane group
    const int m     = lane & 15;
    const int slice = blockIdx.x;  // 0..15
    const int b     = blockIdx.y;  // 0..31

    const float* xw   = x + (size_t)b * C_DIM * N_DIM + slice * 256 + wave * 64;
    const uint4* cwb4 = (const uint4*)(ws_ro + WS_CWB);
    const float* c2p  = ws_ro + WS_C2;

    float* b0 = &buf[0][wave][0];
    float* b1 = &buf[1][wave][0];

    v4f acc[2][4];
    #pragma unroll
    for (int u = 0; u < 2; ++u)
        #pragma unroll
        for (int t = 0; t < 4; ++t) acc[u][t] = (v4f){0.f, 0.f, 0.f, 0.f};

    float f2 = 0.f;
    float sLo[8], sHi[8];
    float fA[16], fB[16];

    // A-fragment prefetch for s=0 (cw bf16, k = 16u+m, c = 8g..8g+7)
    uint4 af0 = cwb4[m * 32 + g];
    uint4 af1 = cwb4[(16 + m) * 32 + g];

    // stage c-step 0: rows c=2i(+1), px=lane; pack c-pairs as bf16 dwords
    #pragma unroll
    for (int i = 0; i < 16; ++i) {
        fA[i] = xw[(size_t)(2 * i) * N_DIM + lane];
        fB[i] = xw[(size_t)(2 * i + 1) * N_DIM + lane];
    }
    #pragma unroll
    for (int i = 0; i < 16; ++i) {
        f2 = fmaf(fA[i], fA[i], f2);
        f2 = fmaf(fB[i], fB[i], f2);
        union { __hip_bfloat16 h; unsigned short u; } lo, hi;
        lo.h = __float2bfloat16(fA[i]);
        hi.h = __float2bfloat16(fB[i]);
        ((unsigned*)b0)[i * RS + lane] = ((unsigned)hi.u << 16) | lo.u;
    }

    #pragma unroll
    for (int s = 0; s < 8; ++s) {
        float* cb = (s & 1) ? b1 : b0;
        float* nb = (s & 1) ? b0 : b1;

        // issue next c-step's loads early (latency hides under MFMA+S phases)
        uint4 naf0, naf1;
        if (s < 7) {
            naf0 = cwb4[m * 32 + 4 * (s + 1) + g];
            naf1 = cwb4[(16 + m) * 32 + 4 * (s + 1) + g];
            #pragma unroll
            for (int i = 0; i < 16; ++i) {
                fA[i] = xw[(size_t)(32 * (s + 1) + 2 * i) * N_DIM + lane];
                fB[i] = xw[(size_t)(32 * (s + 1) + 2 * i + 1) * N_DIM + lane];
            }
        }

        // B-frags (f) + 8 MFMA: D[k][px] += cw[k][c] * f[c][px]
        #pragma unroll
        for (int t = 0; t < 4; ++t) {
            union { unsigned d[4]; v8s v; } fb;
            #pragma unroll
            for (int h = 0; h < 4; ++h)
                fb.d[h] = ((const unsigned*)cb)[(4 * g + h) * RS + 16 * t + m];
            union { uint4 u; v8s v; } a0, a1;
            a0.u = af0; a1.u = af1;
            acc[0][t] = __builtin_amdgcn_mfma_f32_16x16x32_bf16(a0.v, fb.v, acc[0][t], 0, 0, 0);
            acc[1][t] = __builtin_amdgcn_mfma_f32_16x16x32_bf16(a1.v, fb.v, acc[1][t], 0, 0, 0);
        }

        // S row sums from the staged tile: lane owns row m, dword chunk 16g..16g+15
        {
            float aLo = 0.f, aHi = 0.f;
            #pragma unroll
            for (int q = 0; q < 8; ++q) {
                uint2 w = ((const uint2*)cb)[33 * m + 8 * g + q];
                aLo += __uint_as_float(w.x << 16) + __uint_as_float(w.y << 16);
                aHi += __uint_as_float(w.x & 0xffff0000u) + __uint_as_float(w.y & 0xffff0000u);
            }
            aLo += __shfl_xor(aLo, 16); aLo += __shfl_xor(aLo, 32);
            aHi += __shfl_xor(aHi, 16); aHi += __shfl_xor(aHi, 32);
            sLo[s] = aLo; sHi[s] = aHi;
        }

        // pack + write next tile (waits on the global loads issued above)
        if (s < 7) {
            #pragma unroll
            for (int i = 0; i < 16; ++i) {
                f2 = fmaf(fA[i], fA[i], f2);
                f2 = fmaf(fB[i], fB[i], f2);
                union { __hip_bfloat16 h; unsigned short u; } lo, hi;
                lo.h = __float2bfloat16(fA[i]);
                hi.h = __float2bfloat16(fB[i]);
                ((unsigned*)nb)[i * RS + lane] = ((unsigned)hi.u << 16) | lo.u;
            }
            af0 = naf0; af1 = naf1;
        }
    }

    // ---- epilogue: softmax over k (4-lane groups share a pixel) ----
    f2s[wave][lane] = f2;

    float c2v[2][4], scv[2][4];
    #pragma unroll
    for (int u = 0; u < 2; ++u)
        #pragma unroll
        for (int r = 0; r < 4; ++r) {
            int k = 16 * u + 4 * g + r;
            c2v[u][r] = c2p[k];
            scv[u][r] = scale[k];
        }

    float aacc[2][4] = {{0.f,0.f,0.f,0.f},{0.f,0.f,0.f,0.f}};
    #pragma unroll
    for (int t = 0; t < 4; ++t) {
        float f2t = f2s[wave][16 * t + m];   // px = 16t + m
        float L[2][4];
        float mx = -1e30f;
        #pragma unroll
        for (int u = 0; u < 2; ++u)
            #pragma unroll
            for (int r = 0; r < 4; ++r) {
                float d2 = f2t + c2v[u][r] - 2.f * acc[u][t][r];
                float dist = sqrtf(fmaxf(d2, 0.f));
                float Lv = -dist * scv[u][r];
                L[u][r] = Lv;
                mx = fmaxf(mx, Lv);
            }
        mx = fmaxf(mx, __shfl_xor(mx, 16));
        mx = fmaxf(mx, __shfl_xor(mx, 32));
        float e[2][4], ss = 0.f;
        #pragma unroll
        for (int u = 0; u < 2; ++u)
            #pragma unroll
            for (int r = 0; r < 4; ++r) {
                e[u][r] = __expf(L[u][r] - mx);
                ss += e[u][r];
            }
        ss += __shfl_xor(ss, 16);
        ss += __shfl_xor(ss, 32);
        float inv = 1.f / ss;
        #pragma unroll
        for (int u = 0; u < 2; ++u)
            #pragma unroll
            for (int r = 0; r < 4; ++r)
                aacc[u][r] = fmaf(e[u][r], inv, aacc[u][r]);
    }

    // reduce a over the 16 pixels (m lanes) of each group
    #pragma unroll
    for (int u = 0; u < 2; ++u)
        #pragma unroll
        for (int r = 0; r < 4; ++r) {
            float v = aacc[u][r];
            v += __shfl_xor(v, 1);
            v += __shfl_xor(v, 2);
            v += __shfl_xor(v, 4);
            v += __shfl_xor(v, 8);
            if (m == 0) awv[wave][16 * u + 4 * g + r] = v;
        }

    if (g == 0) {
        #pragma unroll
        for (int s = 0; s < 8; ++s) {
            sA[wave][32 * s + 2 * m]     = sLo[s];
            sA[wave][32 * s + 2 * m + 1] = sHi[s];
        }
    }
    __syncthreads();

    float Ssum = sA[0][tid] + sA[1][tid] + sA[2][tid] + sA[3][tid];
    Spart[((size_t)b * NSLICE + slice) * C_DIM + tid] = Ssum;
    if (tid < K_DIM)
        a_part[((size_t)b * NSLICE + slice) * K_DIM + tid] =
            awv[0][tid] + awv[1][tid] + awv[2][tid] + awv[3][tid];
}

__global__ void ce_final(float* __restrict__ out,
                         const float* __restrict__ cw,
                         const float* __restrict__ Spart,
                         const float* __restrict__ a_part) {
    __shared__ float asum[K_DIM];
    const int b = blockIdx.x;
    const int c = threadIdx.x;

    if (c < K_DIM) {
        float a = 0.f;
        #pragma unroll
        for (int s = 0; s < NSLICE; ++s)
            a += a_part[((size_t)b * NSLICE + s) * K_DIM + c];
        asum[c] = a;
    }
    __syncthreads();

    float S = 0.f;
    #pragma unroll
    for (int s = 0; s < NSLICE; ++s)
        S += Spart[((size_t)b * NSLICE + s) * C_DIM + c];

    float acc2 = 0.f;
    #pragma unroll
    for (int k = 0; k < K_DIM; ++k)
        acc2 = fmaf(asum[k], cw[k * C_DIM + c], acc2);  // coalesced over c
    out[b * C_DIM + c] = (S - acc2) * (1.0f / (float)K_DIM);
}

extern "C" void kernel_launch(void* const* d_in, const int* in_sizes, int n_in,
                              void* d_out, int out_size, void* d_ws, size_t ws_size,
                              hipStream_t stream) {
    const float* x     = (const float*)d_in[0];
    const float* cw    = (const float*)d_in[1];
    const float* scale = (const float*)d_in[2];
    float* out = (float*)d_out;
    float* ws  = (float*)d_ws;

    ce_prep<<<1, 256, 0, stream>>>(cw, ws);

    dim3 grid(NSLICE, B_DIM);
    ce_main<<<grid, 256, 0, stream>>>(x, scale, ws,
                                      ws + WS_SPART, ws + WS_APART);

    ce_final<<<B_DIM, 256, 0, stream>>>(out, cw,
                                        ws + WS_SPART, ws + WS_APART);
}